// Round 1
// baseline (1081.577 us; speedup 1.0000x reference)
//
#include <hip/hip_runtime.h>
#include <hip/hip_bf16.h>

#define T_SEQ 2048
#define CDIM 512
#define HDIM 8
#define DHEAD 64
#define BT 4096   // B*T

// ---------------------------------------------------------------------------
// Kernel 1: elementwise tanh of x and the three weight matrices
// ---------------------------------------------------------------------------
__global__ __launch_bounds__(256) void tanh_prep(
    const float* __restrict__ x,  const float* __restrict__ wq,
    const float* __restrict__ wk, const float* __restrict__ wv,
    float* __restrict__ xact, float* __restrict__ wqa,
    float* __restrict__ wka,  float* __restrict__ wva)
{
    const int NX = BT * CDIM / 4;     // 524288 float4
    const int NW = CDIM * CDIM / 4;   // 65536 float4
    int idx = blockIdx.x * 256 + threadIdx.x;
    const float4* src; float4* dst; int off;
    if (idx < NX)           { src = (const float4*)x;  dst = (float4*)xact; off = idx; }
    else if (idx < NX+NW)   { src = (const float4*)wq; dst = (float4*)wqa;  off = idx - NX; }
    else if (idx < NX+2*NW) { src = (const float4*)wk; dst = (float4*)wka;  off = idx - NX - NW; }
    else                    { src = (const float4*)wv; dst = (float4*)wva;  off = idx - NX - 2*NW; }
    float4 t = src[off];
    t.x = tanhf(t.x); t.y = tanhf(t.y); t.z = tanhf(t.z); t.w = tanhf(t.w);
    dst[off] = t;
}

// ---------------------------------------------------------------------------
// Kernel 2: L1-cdist "projection".  out[m][n] = f((0.5 - L1(xact[m],wact[n])/512)*gain[n])
// M=4096, N=512, K=512. 64x64 tile, 256 threads, 4x4 micro-tile, BK=32.
// z selects q (tanh), k (tanh), v (no tanh).
// ---------------------------------------------------------------------------
#define PSTR 36
__global__ __launch_bounds__(256) void proj_l1(
    const float* __restrict__ xact,
    const float* __restrict__ wqa, const float* __restrict__ wka, const float* __restrict__ wva,
    const float* __restrict__ gq,  const float* __restrict__ gk,  const float* __restrict__ gv,
    float* __restrict__ oq, float* __restrict__ okk, float* __restrict__ ov)
{
    __shared__ float As[64][PSTR];
    __shared__ float Bs[64][PSTR];

    const int z = blockIdx.z;
    const float* w    = (z == 0) ? wqa : (z == 1) ? wka : wva;
    const float* gain = (z == 0) ? gq  : (z == 1) ? gk  : gv;
    float* outp       = (z == 0) ? oq  : (z == 1) ? okk : ov;

    const int row0 = blockIdx.y * 64;
    const int col0 = blockIdx.x * 64;
    const int tid = threadIdx.x;
    const int tx = tid & 15, ty = tid >> 4;
    const int lr = tid >> 3;          // 0..31
    const int lc = (tid & 7) * 4;     // 0..28

    float acc[4][4];
    #pragma unroll
    for (int i = 0; i < 4; ++i)
        #pragma unroll
        for (int j = 0; j < 4; ++j) acc[i][j] = 0.f;

    for (int k0 = 0; k0 < CDIM; k0 += 32) {
        float4 a0 = *(const float4*)&xact[(size_t)(row0 + lr)      * CDIM + k0 + lc];
        float4 a1 = *(const float4*)&xact[(size_t)(row0 + lr + 32) * CDIM + k0 + lc];
        float4 b0 = *(const float4*)&w[(size_t)(col0 + lr)      * CDIM + k0 + lc];
        float4 b1 = *(const float4*)&w[(size_t)(col0 + lr + 32) * CDIM + k0 + lc];
        __syncthreads();
        *(float4*)&As[lr][lc]      = a0;
        *(float4*)&As[lr + 32][lc] = a1;
        *(float4*)&Bs[lr][lc]      = b0;
        *(float4*)&Bs[lr + 32][lc] = b1;
        __syncthreads();

        #pragma unroll
        for (int kk = 0; kk < 32; kk += 4) {
            float4 a4[4], b4[4];
            #pragma unroll
            for (int i = 0; i < 4; ++i) a4[i] = *(const float4*)&As[ty*4 + i][kk];
            #pragma unroll
            for (int j = 0; j < 4; ++j) b4[j] = *(const float4*)&Bs[tx*4 + j][kk];
            #pragma unroll
            for (int i = 0; i < 4; ++i)
                #pragma unroll
                for (int j = 0; j < 4; ++j)
                    acc[i][j] += fabsf(a4[i].x - b4[j].x) + fabsf(a4[i].y - b4[j].y)
                               + fabsf(a4[i].z - b4[j].z) + fabsf(a4[i].w - b4[j].w);
        }
    }

    #pragma unroll
    for (int i = 0; i < 4; ++i) {
        const int r = row0 + ty*4 + i;
        #pragma unroll
        for (int j = 0; j < 4; ++j) {
            const int c = col0 + tx*4 + j;
            float val = (0.5f - acc[i][j] * (1.0f / 512.0f)) * gain[c];
            if (z < 2) val = tanhf(val);
            outp[(size_t)r * CDIM + c] = val;
        }
    }
}

// ---------------------------------------------------------------------------
// Kernel 3: causal L1-kernel attention.
// Grid: (32 i-blocks remapped for balance, 16 bh). Block 256 thr.
// q/k/v in (B,T,C) layout; head h = cols h*64..h*64+63.
// ---------------------------------------------------------------------------
#define ASTR 68
__global__ __launch_bounds__(256) void attn_l1(
    const float* __restrict__ qg, const float* __restrict__ kg, const float* __restrict__ vg,
    const float* __restrict__ gamma, const float* __restrict__ rho,
    float* __restrict__ outg)
{
    __shared__ float Qs[64][ASTR];
    __shared__ float KWs[64][ASTR];   // K tile, later reused for score tile W
    __shared__ float Vs[64][ASTR];

    const int bh = blockIdx.y;
    const int b = bh >> 3, h = bh & 7;
    // balance causal work: pair small-it with large-it in consecutive block ids
    const int xb = blockIdx.x;
    const int it = (xb & 1) ? (31 - (xb >> 1)) : (xb >> 1);
    const int i0 = it * 64;
    const int tid = threadIdx.x;
    const int tx = tid & 15, ty = tid >> 4;

    const float gp = log1pf(__expf(gamma[h]));
    const float rp = log1pf(__expf(rho[h]));

    const size_t hb = (size_t)b * T_SEQ * CDIM + h * DHEAD;

    {   // load Q tile (64 rows x 64 cols)
        const int lr = tid >> 4;          // 0..15
        const int lc = (tid & 15) * 4;    // 0..60
        #pragma unroll
        for (int p = 0; p < 4; ++p) {
            const int r = p * 16 + lr;
            *(float4*)&Qs[r][lc] = *(const float4*)&qg[hb + (size_t)(i0 + r) * CDIM + lc];
        }
    }

    float acc_v[4][4];
    float acc_s[4];
    #pragma unroll
    for (int i = 0; i < 4; ++i) {
        acc_s[i] = 0.f;
        #pragma unroll
        for (int j = 0; j < 4; ++j) acc_v[i][j] = 0.f;
    }

    const int nt = it + 1;
    for (int jt = 0; jt < nt; ++jt) {
        const int j0 = jt * 64;
        __syncthreads();   // previous PV done before overwriting K/V
        {
            const int lr = tid >> 4;
            const int lc = (tid & 15) * 4;
            #pragma unroll
            for (int p = 0; p < 4; ++p) {
                const int r = p * 16 + lr;
                *(float4*)&KWs[r][lc] = *(const float4*)&kg[hb + (size_t)(j0 + r) * CDIM + lc];
                *(float4*)&Vs[r][lc]  = *(const float4*)&vg[hb + (size_t)(j0 + r) * CDIM + lc];
            }
        }
        __syncthreads();

        // ---- scores: L1 over d=64 ----
        float l1[4][4];
        #pragma unroll
        for (int i = 0; i < 4; ++i)
            #pragma unroll
            for (int j = 0; j < 4; ++j) l1[i][j] = 0.f;

        #pragma unroll
        for (int d0 = 0; d0 < DHEAD; d0 += 4) {
            float4 q4[4], k4[4];
            #pragma unroll
            for (int i = 0; i < 4; ++i) q4[i] = *(const float4*)&Qs[ty*4 + i][d0];
            #pragma unroll
            for (int j = 0; j < 4; ++j) k4[j] = *(const float4*)&KWs[tx*4 + j][d0];
            #pragma unroll
            for (int i = 0; i < 4; ++i)
                #pragma unroll
                for (int j = 0; j < 4; ++j)
                    l1[i][j] += fabsf(q4[i].x - k4[j].x) + fabsf(q4[i].y - k4[j].y)
                              + fabsf(q4[i].z - k4[j].z) + fabsf(q4[i].w - k4[j].w);
        }

        // ---- kernel function + causal mask ----
        float wmat[4][4];
        const bool diag = (jt == nt - 1);
        #pragma unroll
        for (int i = 0; i < 4; ++i)
            #pragma unroll
            for (int j = 0; j < 4; ++j) {
                const float s = l1[i][j] * 0.125f;            // (l1/64)*sqrt(64)
                const float den = 1.0f + gp * (s * s) + 1e-6f;
                float wgt = __expf(-rp * __logf(den));        // den^(-rho)
                if (diag && (tx*4 + j) > (ty*4 + i)) wgt = 0.0f;
                wmat[i][j] = wgt;
            }

        // ---- row sums (reduce over tx group of 16 lanes) ----
        #pragma unroll
        for (int i = 0; i < 4; ++i) {
            float rs = wmat[i][0] + wmat[i][1] + wmat[i][2] + wmat[i][3];
            rs += __shfl_xor(rs, 1, 64);
            rs += __shfl_xor(rs, 2, 64);
            rs += __shfl_xor(rs, 4, 64);
            rs += __shfl_xor(rs, 8, 64);
            acc_s[i] += rs;
        }

        __syncthreads();   // everyone done reading K before overwrite with W
        #pragma unroll
        for (int i = 0; i < 4; ++i)
            *(float4*)&KWs[ty*4 + i][tx*4] =
                make_float4(wmat[i][0], wmat[i][1], wmat[i][2], wmat[i][3]);
        __syncthreads();

        // ---- PV: acc_v[i][dd] += sum_j W[i][j] * V[j][dd], dd = tx*4.. ----
        #pragma unroll
        for (int j = 0; j < 64; j += 4) {
            float4 w4[4], v4[4];
            #pragma unroll
            for (int i = 0; i < 4; ++i)  w4[i]  = *(const float4*)&KWs[ty*4 + i][j];
            #pragma unroll
            for (int jj = 0; jj < 4; ++jj) v4[jj] = *(const float4*)&Vs[j + jj][tx*4];
            #pragma unroll
            for (int i = 0; i < 4; ++i) {
                acc_v[i][0] += w4[i].x*v4[0].x + w4[i].y*v4[1].x + w4[i].z*v4[2].x + w4[i].w*v4[3].x;
                acc_v[i][1] += w4[i].x*v4[0].y + w4[i].y*v4[1].y + w4[i].z*v4[2].y + w4[i].w*v4[3].y;
                acc_v[i][2] += w4[i].x*v4[0].z + w4[i].y*v4[1].z + w4[i].z*v4[2].z + w4[i].w*v4[3].z;
                acc_v[i][3] += w4[i].x*v4[0].w + w4[i].y*v4[1].w + w4[i].z*v4[2].w + w4[i].w*v4[3].w;
            }
        }
    }

    // ---- epilogue: normalize and store into (B,T,C) ----
    #pragma unroll
    for (int i = 0; i < 4; ++i) {
        const float inv = 1.0f / (acc_s[i] + 1e-6f);
        const int r = i0 + ty*4 + i;
        #pragma unroll
        for (int c = 0; c < 4; ++c)
            outg[hb + (size_t)r * CDIM + tx*4 + c] = acc_v[i][c] * inv;
    }
}

// ---------------------------------------------------------------------------
// Kernel 4: output projection Y = A @ wo^T + bias. M=4096, N=512, K=512.
// ---------------------------------------------------------------------------
__global__ __launch_bounds__(256) void out_gemm(
    const float* __restrict__ A, const float* __restrict__ wo,
    const float* __restrict__ bias, float* __restrict__ Y)
{
    __shared__ float As[64][PSTR];
    __shared__ float Bs[64][PSTR];

    const int row0 = blockIdx.y * 64;
    const int col0 = blockIdx.x * 64;
    const int tid = threadIdx.x;
    const int tx = tid & 15, ty = tid >> 4;
    const int lr = tid >> 3;
    const int lc = (tid & 7) * 4;

    float acc[4][4];
    #pragma unroll
    for (int i = 0; i < 4; ++i)
        #pragma unroll
        for (int j = 0; j < 4; ++j) acc[i][j] = 0.f;

    for (int k0 = 0; k0 < CDIM; k0 += 32) {
        float4 a0 = *(const float4*)&A[(size_t)(row0 + lr)      * CDIM + k0 + lc];
        float4 a1 = *(const float4*)&A[(size_t)(row0 + lr + 32) * CDIM + k0 + lc];
        float4 b0 = *(const float4*)&wo[(size_t)(col0 + lr)      * CDIM + k0 + lc];
        float4 b1 = *(const float4*)&wo[(size_t)(col0 + lr + 32) * CDIM + k0 + lc];
        __syncthreads();
        *(float4*)&As[lr][lc]      = a0;
        *(float4*)&As[lr + 32][lc] = a1;
        *(float4*)&Bs[lr][lc]      = b0;
        *(float4*)&Bs[lr + 32][lc] = b1;
        __syncthreads();

        #pragma unroll
        for (int kk = 0; kk < 32; kk += 4) {
            float4 a4[4], b4[4];
            #pragma unroll
            for (int i = 0; i < 4; ++i) a4[i] = *(const float4*)&As[ty*4 + i][kk];
            #pragma unroll
            for (int j = 0; j < 4; ++j) b4[j] = *(const float4*)&Bs[tx*4 + j][kk];
            #pragma unroll
            for (int i = 0; i < 4; ++i)
                #pragma unroll
                for (int j = 0; j < 4; ++j)
                    acc[i][j] += a4[i].x * b4[j].x + a4[i].y * b4[j].y
                               + a4[i].z * b4[j].z + a4[i].w * b4[j].w;
        }
    }

    #pragma unroll
    for (int i = 0; i < 4; ++i) {
        const int r = row0 + ty*4 + i;
        #pragma unroll
        for (int j = 0; j < 4; ++j) {
            const int c = col0 + tx*4 + j;
            Y[(size_t)r * CDIM + c] = acc[i][j] + bias[c];
        }
    }
}

// ---------------------------------------------------------------------------
extern "C" void kernel_launch(void* const* d_in, const int* in_sizes, int n_in,
                              void* d_out, int out_size, void* d_ws, size_t ws_size,
                              hipStream_t stream)
{
    (void)in_sizes; (void)n_in; (void)out_size; (void)ws_size;
    const float* x     = (const float*)d_in[0];
    // d_in[1] = mask (causal tril; semantics hardcoded)
    const float* wq    = (const float*)d_in[2];
    const float* gq    = (const float*)d_in[3];
    const float* wk    = (const float*)d_in[4];
    const float* gk    = (const float*)d_in[5];
    const float* wv    = (const float*)d_in[6];
    const float* gv    = (const float*)d_in[7];
    const float* wo    = (const float*)d_in[8];
    const float* wob   = (const float*)d_in[9];
    const float* gamma = (const float*)d_in[10];
    const float* rho   = (const float*)d_in[11];
    float* out = (float*)d_out;

    float* ws   = (float*)d_ws;
    float* xact = ws;                       // 4096*512
    float* wqa  = xact + (size_t)BT * CDIM; // 512*512
    float* wka  = wqa + CDIM * CDIM;
    float* wva  = wka + CDIM * CDIM;
    float* qb   = wva + CDIM * CDIM;        // 4096*512
    float* kb   = qb + (size_t)BT * CDIM;
    float* vb   = kb + (size_t)BT * CDIM;
    float* ab   = vb + (size_t)BT * CDIM;   // attention out (B,T,C)

    tanh_prep<<<2816, 256, 0, stream>>>(x, wq, wk, wv, xact, wqa, wka, wva);
    proj_l1<<<dim3(8, 64, 3), 256, 0, stream>>>(xact, wqa, wka, wva,
                                                gq, gk, gv, qb, kb, vb);
    attn_l1<<<dim3(32, 16), 256, 0, stream>>>(qb, kb, vb, gamma, rho, ab);
    out_gemm<<<dim3(8, 64), 256, 0, stream>>>(ab, wo, wob, out);
}

// Round 2
// 808.165 us; speedup vs baseline: 1.3383x; 1.3383x over previous
//
#include <hip/hip_runtime.h>
#include <hip/hip_bf16.h>

#define T_SEQ 2048
#define CDIM 512
#define HDIM 8
#define DHEAD 64
#define BT 4096   // B*T

// ---------------------------------------------------------------------------
// Kernel 1: elementwise tanh of x and the three weight matrices
// ---------------------------------------------------------------------------
__global__ __launch_bounds__(256) void tanh_prep(
    const float* __restrict__ x,  const float* __restrict__ wq,
    const float* __restrict__ wk, const float* __restrict__ wv,
    float* __restrict__ xact, float* __restrict__ wqa,
    float* __restrict__ wka,  float* __restrict__ wva)
{
    const int NX = BT * CDIM / 4;     // 524288 float4
    const int NW = CDIM * CDIM / 4;   // 65536 float4
    int idx = blockIdx.x * 256 + threadIdx.x;
    const float4* src; float4* dst; int off;
    if (idx < NX)           { src = (const float4*)x;  dst = (float4*)xact; off = idx; }
    else if (idx < NX+NW)   { src = (const float4*)wq; dst = (float4*)wqa;  off = idx - NX; }
    else if (idx < NX+2*NW) { src = (const float4*)wk; dst = (float4*)wka;  off = idx - NX - NW; }
    else                    { src = (const float4*)wv; dst = (float4*)wva;  off = idx - NX - 2*NW; }
    float4 t = src[off];
    t.x = tanhf(t.x); t.y = tanhf(t.y); t.z = tanhf(t.z); t.w = tanhf(t.w);
    dst[off] = t;
}

// ---------------------------------------------------------------------------
// Kernel 2: zero the attention accumulators (accv: BT*CDIM, accs: BT*HDIM)
// ---------------------------------------------------------------------------
__global__ __launch_bounds__(256) void zero_accum(float* __restrict__ accv,
                                                  float* __restrict__ accs)
{
    const int NV = BT * CDIM / 4;   // 524288
    int idx = blockIdx.x * 256 + threadIdx.x;
    if (idx < NV) ((float4*)accv)[idx] = make_float4(0.f, 0.f, 0.f, 0.f);
    else          ((float4*)accs)[idx - NV] = make_float4(0.f, 0.f, 0.f, 0.f);
}

// ---------------------------------------------------------------------------
// Kernel 3: L1-cdist projection. out[m][n] = f((0.5 - L1(x[m],w[n])/512)*gain[n])
// M=4096, N=512, K=512. 64x64 tile, 256 threads.
// Micro-tile rows: a-rows = ty+16i, b-rows = tx+16j (stride-16 -> bank-spread).
// ---------------------------------------------------------------------------
#define PSTR 36
__global__ __launch_bounds__(256) void proj_l1(
    const float* __restrict__ xact,
    const float* __restrict__ wqa, const float* __restrict__ wka, const float* __restrict__ wva,
    const float* __restrict__ gq,  const float* __restrict__ gk,  const float* __restrict__ gv,
    float* __restrict__ oq, float* __restrict__ okk, float* __restrict__ ov)
{
    __shared__ float As[64][PSTR];
    __shared__ float Bs[64][PSTR];

    const int z = blockIdx.z;
    const float* w    = (z == 0) ? wqa : (z == 1) ? wka : wva;
    const float* gain = (z == 0) ? gq  : (z == 1) ? gk  : gv;
    float* outp       = (z == 0) ? oq  : (z == 1) ? okk : ov;

    const int row0 = blockIdx.y * 64;
    const int col0 = blockIdx.x * 64;
    const int tid = threadIdx.x;
    const int tx = tid & 15, ty = tid >> 4;
    const int lr = tid >> 3;          // 0..31
    const int lc = (tid & 7) * 4;     // 0..28

    float acc[4][4];
    #pragma unroll
    for (int i = 0; i < 4; ++i)
        #pragma unroll
        for (int j = 0; j < 4; ++j) acc[i][j] = 0.f;

    for (int k0 = 0; k0 < CDIM; k0 += 32) {
        float4 a0 = *(const float4*)&xact[(size_t)(row0 + lr)      * CDIM + k0 + lc];
        float4 a1 = *(const float4*)&xact[(size_t)(row0 + lr + 32) * CDIM + k0 + lc];
        float4 b0 = *(const float4*)&w[(size_t)(col0 + lr)      * CDIM + k0 + lc];
        float4 b1 = *(const float4*)&w[(size_t)(col0 + lr + 32) * CDIM + k0 + lc];
        __syncthreads();
        *(float4*)&As[lr][lc]      = a0;
        *(float4*)&As[lr + 32][lc] = a1;
        *(float4*)&Bs[lr][lc]      = b0;
        *(float4*)&Bs[lr + 32][lc] = b1;
        __syncthreads();

        #pragma unroll
        for (int kk = 0; kk < 32; kk += 4) {
            float4 a4[4], b4[4];
            #pragma unroll
            for (int i = 0; i < 4; ++i) a4[i] = *(const float4*)&As[ty + 16*i][kk];
            #pragma unroll
            for (int j = 0; j < 4; ++j) b4[j] = *(const float4*)&Bs[tx + 16*j][kk];
            #pragma unroll
            for (int i = 0; i < 4; ++i)
                #pragma unroll
                for (int j = 0; j < 4; ++j)
                    acc[i][j] += fabsf(a4[i].x - b4[j].x) + fabsf(a4[i].y - b4[j].y)
                               + fabsf(a4[i].z - b4[j].z) + fabsf(a4[i].w - b4[j].w);
        }
    }

    float gcol[4];
    #pragma unroll
    for (int j = 0; j < 4; ++j) gcol[j] = gain[col0 + tx + 16*j];

    #pragma unroll
    for (int i = 0; i < 4; ++i) {
        const int r = row0 + ty + 16*i;
        #pragma unroll
        for (int j = 0; j < 4; ++j) {
            const int c = col0 + tx + 16*j;
            float val = (0.5f - acc[i][j] * (1.0f / 512.0f)) * gcol[j];
            if (z < 2) val = tanhf(val);
            outp[(size_t)r * CDIM + c] = val;
        }
    }
}

// ---------------------------------------------------------------------------
// Kernel 4: causal L1-kernel attention, split along KV into <=4-tile chunks.
// Grid: (144 chunk-ids, 16 bh). Partial (sum w*v, sum w) via atomicAdd.
// ---------------------------------------------------------------------------
#define ASTR 68
__global__ __launch_bounds__(256) void attn_l1(
    const float* __restrict__ qg, const float* __restrict__ kg, const float* __restrict__ vg,
    const float* __restrict__ gamma, const float* __restrict__ rho,
    float* __restrict__ accv, float* __restrict__ accs)
{
    __shared__ float Qs[64][ASTR];
    __shared__ float KWs[64][ASTR];   // K tile, later reused for score tile W
    __shared__ float Vs[64][ASTR];

    const int bh = blockIdx.y;
    const int b = bh >> 3, h = bh & 7;

    // decode chunk id x -> (it, chunk c): it in group g=it>>2 has g+1 chunks
    const int x = blockIdx.x;
    int g = 0;
    while (2*(g+1)*(g+2) <= x) ++g;           // <= 7 iterations
    const int rr = x - 2*g*(g+1);
    const int it = 4*g + rr / (g+1);
    const int cc = rr % (g+1);
    const int i0 = it * 64;
    const int jt0 = 4*cc;
    const int jt1 = min(jt0 + 3, it);

    const int tid = threadIdx.x;
    const int tx = tid & 15, ty = tid >> 4;

    const float gp = log1pf(__expf(gamma[h]));
    const float rp = log1pf(__expf(rho[h]));

    const size_t hb = (size_t)b * T_SEQ * CDIM + h * DHEAD;

    {   // load Q tile (64 rows x 64 cols)
        const int lr = tid >> 4;          // 0..15
        const int lc = (tid & 15) * 4;    // 0..60
        #pragma unroll
        for (int p = 0; p < 4; ++p) {
            const int r = p * 16 + lr;
            *(float4*)&Qs[r][lc] = *(const float4*)&qg[hb + (size_t)(i0 + r) * CDIM + lc];
        }
    }

    float acc_v[4][4];
    float acc_s[4];
    #pragma unroll
    for (int i = 0; i < 4; ++i) {
        acc_s[i] = 0.f;
        #pragma unroll
        for (int j = 0; j < 4; ++j) acc_v[i][j] = 0.f;
    }

    for (int jt = jt0; jt <= jt1; ++jt) {
        const int j0 = jt * 64;
        __syncthreads();   // previous PV done before overwriting K/V
        {
            const int lr = tid >> 4;
            const int lc = (tid & 15) * 4;
            #pragma unroll
            for (int p = 0; p < 4; ++p) {
                const int r = p * 16 + lr;
                *(float4*)&KWs[r][lc] = *(const float4*)&kg[hb + (size_t)(j0 + r) * CDIM + lc];
                *(float4*)&Vs[r][lc]  = *(const float4*)&vg[hb + (size_t)(j0 + r) * CDIM + lc];
            }
        }
        __syncthreads();

        // ---- scores: L1 over d=64; q-rows ty+16i, k-rows tx+16j ----
        float l1[4][4];
        #pragma unroll
        for (int i = 0; i < 4; ++i)
            #pragma unroll
            for (int j = 0; j < 4; ++j) l1[i][j] = 0.f;

        #pragma unroll
        for (int d0 = 0; d0 < DHEAD; d0 += 4) {
            float4 q4[4], k4[4];
            #pragma unroll
            for (int i = 0; i < 4; ++i) q4[i] = *(const float4*)&Qs[ty + 16*i][d0];
            #pragma unroll
            for (int j = 0; j < 4; ++j) k4[j] = *(const float4*)&KWs[tx + 16*j][d0];
            #pragma unroll
            for (int i = 0; i < 4; ++i)
                #pragma unroll
                for (int j = 0; j < 4; ++j)
                    l1[i][j] += fabsf(q4[i].x - k4[j].x) + fabsf(q4[i].y - k4[j].y)
                              + fabsf(q4[i].z - k4[j].z) + fabsf(q4[i].w - k4[j].w);
        }

        // ---- kernel function + causal mask ----
        float wmat[4][4];
        #pragma unroll
        for (int i = 0; i < 4; ++i)
            #pragma unroll
            for (int j = 0; j < 4; ++j) {
                const float s = l1[i][j] * 0.125f;            // (l1/64)*sqrt(64)
                const float den = 1.0f + gp * (s * s) + 1e-6f;
                float wgt = __expf(-rp * __logf(den));        // den^(-rho)
                if ((j0 + tx + 16*j) > (i0 + ty + 16*i)) wgt = 0.0f;
                wmat[i][j] = wgt;
            }

        // ---- row sums (reduce over the 16 tx lanes) ----
        #pragma unroll
        for (int i = 0; i < 4; ++i) {
            float rs = wmat[i][0] + wmat[i][1] + wmat[i][2] + wmat[i][3];
            rs += __shfl_xor(rs, 1, 64);
            rs += __shfl_xor(rs, 2, 64);
            rs += __shfl_xor(rs, 4, 64);
            rs += __shfl_xor(rs, 8, 64);
            acc_s[i] += rs;
        }

        __syncthreads();   // everyone done reading K before overwrite with W
        #pragma unroll
        for (int i = 0; i < 4; ++i)
            #pragma unroll
            for (int j = 0; j < 4; ++j)
                KWs[ty + 16*i][tx + 16*j] = wmat[i][j];   // W[q-row][k-idx]
        __syncthreads();

        // ---- PV: acc_v[i][c] += sum_j W[qrow][j] * V[j][4tx+c] ----
        #pragma unroll
        for (int jc = 0; jc < 64; jc += 4) {
            float4 w4[4], v4[4];
            #pragma unroll
            for (int i = 0; i < 4; ++i)  w4[i]  = *(const float4*)&KWs[ty + 16*i][jc];
            #pragma unroll
            for (int jj = 0; jj < 4; ++jj) v4[jj] = *(const float4*)&Vs[jc + jj][tx*4];
            #pragma unroll
            for (int i = 0; i < 4; ++i) {
                acc_v[i][0] += w4[i].x*v4[0].x + w4[i].y*v4[1].x + w4[i].z*v4[2].x + w4[i].w*v4[3].x;
                acc_v[i][1] += w4[i].x*v4[0].y + w4[i].y*v4[1].y + w4[i].z*v4[2].y + w4[i].w*v4[3].y;
                acc_v[i][2] += w4[i].x*v4[0].z + w4[i].y*v4[1].z + w4[i].z*v4[2].z + w4[i].w*v4[3].z;
                acc_v[i][3] += w4[i].x*v4[0].w + w4[i].y*v4[1].w + w4[i].z*v4[2].w + w4[i].w*v4[3].w;
            }
        }
    }

    // ---- epilogue: atomically accumulate partials ----
    #pragma unroll
    for (int i = 0; i < 4; ++i) {
        const int qr = i0 + ty + 16*i;
        if (tx == 0)
            atomicAdd(&accs[(size_t)(b * T_SEQ + qr) * HDIM + h], acc_s[i]);
        #pragma unroll
        for (int c = 0; c < 4; ++c)
            atomicAdd(&accv[hb + (size_t)qr * CDIM + tx*4 + c], acc_v[i][c]);
    }
}

// ---------------------------------------------------------------------------
// Kernel 5: normalize attention output: ab = accv / (accs + 1e-6)
// ---------------------------------------------------------------------------
__global__ __launch_bounds__(256) void normalize_k(
    const float* __restrict__ accv, const float* __restrict__ accs,
    float* __restrict__ ab)
{
    int idx = blockIdx.x * 256 + threadIdx.x;   // < 524288 float4
    const int row = idx >> 7;          // 128 float4 per row of 512
    const int col = (idx & 127) << 2;
    const int h = col >> 6;
    const float s = accs[(size_t)row * HDIM + h];
    const float inv = 1.0f / (s + 1e-6f);
    float4 v = ((const float4*)accv)[idx];
    v.x *= inv; v.y *= inv; v.z *= inv; v.w *= inv;
    ((float4*)ab)[idx] = v;
}

// ---------------------------------------------------------------------------
// Kernel 6: output projection Y = A @ wo^T + bias. M=4096, N=512, K=512.
// ---------------------------------------------------------------------------
__global__ __launch_bounds__(256) void out_gemm(
    const float* __restrict__ A, const float* __restrict__ wo,
    const float* __restrict__ bias, float* __restrict__ Y)
{
    __shared__ float As[64][PSTR];
    __shared__ float Bs[64][PSTR];

    const int row0 = blockIdx.y * 64;
    const int col0 = blockIdx.x * 64;
    const int tid = threadIdx.x;
    const int tx = tid & 15, ty = tid >> 4;
    const int lr = tid >> 3;
    const int lc = (tid & 7) * 4;

    float acc[4][4];
    #pragma unroll
    for (int i = 0; i < 4; ++i)
        #pragma unroll
        for (int j = 0; j < 4; ++j) acc[i][j] = 0.f;

    for (int k0 = 0; k0 < CDIM; k0 += 32) {
        float4 a0 = *(const float4*)&A[(size_t)(row0 + lr)      * CDIM + k0 + lc];
        float4 a1 = *(const float4*)&A[(size_t)(row0 + lr + 32) * CDIM + k0 + lc];
        float4 b0 = *(const float4*)&wo[(size_t)(col0 + lr)      * CDIM + k0 + lc];
        float4 b1 = *(const float4*)&wo[(size_t)(col0 + lr + 32) * CDIM + k0 + lc];
        __syncthreads();
        *(float4*)&As[lr][lc]      = a0;
        *(float4*)&As[lr + 32][lc] = a1;
        *(float4*)&Bs[lr][lc]      = b0;
        *(float4*)&Bs[lr + 32][lc] = b1;
        __syncthreads();

        #pragma unroll
        for (int kk = 0; kk < 32; kk += 4) {
            float4 a4[4], b4[4];
            #pragma unroll
            for (int i = 0; i < 4; ++i) a4[i] = *(const float4*)&As[ty + 16*i][kk];
            #pragma unroll
            for (int j = 0; j < 4; ++j) b4[j] = *(const float4*)&Bs[tx + 16*j][kk];
            #pragma unroll
            for (int i = 0; i < 4; ++i)
                #pragma unroll
                for (int j = 0; j < 4; ++j)
                    acc[i][j] += a4[i].x * b4[j].x + a4[i].y * b4[j].y
                               + a4[i].z * b4[j].z + a4[i].w * b4[j].w;
        }
    }

    float bcol[4];
    #pragma unroll
    for (int j = 0; j < 4; ++j) bcol[j] = bias[col0 + tx + 16*j];

    #pragma unroll
    for (int i = 0; i < 4; ++i) {
        const int r = row0 + ty + 16*i;
        #pragma unroll
        for (int j = 0; j < 4; ++j) {
            const int c = col0 + tx + 16*j;
            Y[(size_t)r * CDIM + c] = acc[i][j] + bcol[j];
        }
    }
}

// ---------------------------------------------------------------------------
extern "C" void kernel_launch(void* const* d_in, const int* in_sizes, int n_in,
                              void* d_out, int out_size, void* d_ws, size_t ws_size,
                              hipStream_t stream)
{
    (void)in_sizes; (void)n_in; (void)out_size; (void)ws_size;
    const float* x     = (const float*)d_in[0];
    // d_in[1] = mask (causal tril; semantics hardcoded)
    const float* wq    = (const float*)d_in[2];
    const float* gq    = (const float*)d_in[3];
    const float* wk    = (const float*)d_in[4];
    const float* gk    = (const float*)d_in[5];
    const float* wv    = (const float*)d_in[6];
    const float* gv    = (const float*)d_in[7];
    const float* wo    = (const float*)d_in[8];
    const float* wob   = (const float*)d_in[9];
    const float* gamma = (const float*)d_in[10];
    const float* rho   = (const float*)d_in[11];
    float* out = (float*)d_out;

    float* ws   = (float*)d_ws;
    float* xact = ws;                       // 4096*512 (later reused as accv)
    float* wqa  = xact + (size_t)BT * CDIM; // 512*512
    float* wka  = wqa + CDIM * CDIM;
    float* wva  = wka + CDIM * CDIM;
    float* qb   = wva + CDIM * CDIM;        // 4096*512 (later reused as ab)
    float* kb   = qb + (size_t)BT * CDIM;
    float* vb   = kb + (size_t)BT * CDIM;
    float* accs = vb + (size_t)BT * CDIM;   // 4096*8
    float* accv = xact;                     // alias: xact dead after proj_l1
    float* ab   = qb;                       // alias: qb dead after attn_l1

    tanh_prep<<<2816, 256, 0, stream>>>(x, wq, wk, wv, xact, wqa, wka, wva);
    proj_l1<<<dim3(8, 64, 3), 256, 0, stream>>>(xact, wqa, wka, wva,
                                                gq, gk, gv, qb, kb, vb);
    zero_accum<<<2081, 256, 0, stream>>>(accv, accs);
    attn_l1<<<dim3(144, 16), 256, 0, stream>>>(qb, kb, vb, gamma, rho, accv, accs);
    normalize_k<<<2048, 256, 0, stream>>>(accv, accs, ab);
    out_gemm<<<dim3(8, 64), 256, 0, stream>>>(ab, wo, wob, out);
}